// Round 9
// baseline (16887.001 us; speedup 1.0000x reference)
//
#include <hip/hip_runtime.h>
#include <hip/hip_bf16.h>

#define VOCAB 32000
#define EMBED 512
#define ENCD  512
#define HID   1024
#define ATTN  128
#define SRC   1024
#define TGT   512
#define NB    32          // blocks for the per-step kernel

typedef __hip_bfloat16 bf16;
typedef _Float16 f16;
typedef __attribute__((ext_vector_type(2))) _Float16 f16x2;
typedef __attribute__((ext_vector_type(8))) _Float16 f16x8;
typedef __attribute__((ext_vector_type(8))) short bf16x8v;
typedef __attribute__((ext_vector_type(4))) float f32x4;

// ---- workspace layout (float offsets), 23.6 MB total ----
#define OFF_T    0           // f16 [1024][128]  T = clamp(tanh(enc_proj))
#define OFF_G    65536       // f16 [512][4096]  gate bases, prow-permuted
#define OFF_HH   1114112     // f32 [513][1024]  h history
#define OFF_CC   1639424     // f32 [1024]       c state
#define OFF_WAH  1640448     // f16 [128][1024]  Wa_h
#define OFF_WHH  1705984     // f16 [4096][1024] W_hh, prow-permuted
#define OFF_VT   3803136     // f16 [4096][1024] V[prow][s] = Wihc[prow]·enc[s]
// end = 5900288 floats = 23.6 MB

__device__ __forceinline__ float sigm(float x){ return 1.f/(1.f+__expf(-x)); }
__device__ __forceinline__ float tanh_f(float x){
  float ax = fabsf(x);
  float e = __expf(-2.f*ax);
  float r = (1.f - e) / (1.f + e);
  return copysignf(r, x);
}
__device__ __forceinline__ short f2bs(float x){
  union { bf16 h; short s; } u; u.h = __float2bfloat16(x); return u.s;
}
__device__ __forceinline__ bf16x8v cvt8(const float* p){
  float4 a = *reinterpret_cast<const float4*>(p);
  float4 b = *reinterpret_cast<const float4*>(p+4);
  bf16x8v r;
  r[0]=f2bs(a.x); r[1]=f2bs(a.y); r[2]=f2bs(a.z); r[3]=f2bs(a.w);
  r[4]=f2bs(b.x); r[5]=f2bs(b.y); r[6]=f2bs(b.z); r[7]=f2bs(b.w);
  return r;
}

// ---- one-time: T[s][a] = clamp(tanh(enc[s]·Wa_enc[a])) f16  (grid 64 x 128) ----
__global__ void k_encT(const float* __restrict__ enc, const float* __restrict__ Wa_enc,
                       f16* __restrict__ Tt){
  __shared__ float eL[16][ENCD];
  int s0 = blockIdx.x*16, tid = threadIdx.x;
  #pragma unroll
  for (int i=0;i<16;i++){
    int li = tid + i*128;
    int t = li>>7, k4 = li&127;
    *reinterpret_cast<float4*>(&eL[t][k4*4]) =
      *reinterpret_cast<const float4*>(enc + (size_t)(s0+t)*ENCD + k4*4);
  }
  __syncthreads();
  const float* w = Wa_enc + (size_t)tid*ENCD;
  float acc[16];
  #pragma unroll
  for (int t=0;t<16;t++) acc[t]=0.f;
  for (int k4=0;k4<128;k4++){
    float4 wv = *reinterpret_cast<const float4*>(w + k4*4);
    #pragma unroll
    for (int t=0;t<16;t++){
      float4 e4 = *reinterpret_cast<const float4*>(&eL[t][k4*4]);
      acc[t] += wv.x*e4.x + wv.y*e4.y + wv.z*e4.z + wv.w*e4.w;
    }
  }
  #pragma unroll
  for (int t=0;t<16;t++){
    float th = tanh_f(acc[t]);
    th = fminf(0.9995f, fmaxf(-0.9995f, th));   // guard tanh-identity 0/0 corner
    Tt[(size_t)(s0+t)*ATTN + tid] = (f16)th;
  }
}

// ---- one-time: Gp[t][prow] f16, prow = (j>>5)*128 + g*32 + (j&31) ----
__global__ void k_gbase(const int* __restrict__ sos, const int* __restrict__ tgt,
                        const float* __restrict__ embt, const float* __restrict__ W_ih,
                        const float* __restrict__ b_ih, const float* __restrict__ b_hh,
                        f16* __restrict__ Gp){
  __shared__ float eL[16][EMBED];
  int tid = threadIdx.x;
  int t0 = blockIdx.y*16;
  #pragma unroll
  for (int i=0;i<8;i++){
    int li = tid + i*256;
    int t = li>>7, k4 = li&127;
    int tg = t0 + t;
    int tok = (tg==0) ? sos[0] : tgt[tg-1];
    *reinterpret_cast<float4*>(&eL[t][k4*4]) =
      *reinterpret_cast<const float4*>(embt + (size_t)tok*EMBED + k4*4);
  }
  __syncthreads();
  int r = blockIdx.x*256 + tid;
  int g = r>>10, j = r&1023;
  int prow = (j>>5)*128 + g*32 + (j&31);
  const float* w = W_ih + (size_t)r*(EMBED+ENCD);
  float base = b_ih[r] + b_hh[r];
  float acc[16];
  #pragma unroll
  for (int t=0;t<16;t++) acc[t]=0.f;
  for (int k4=0;k4<128;k4++){
    float4 wv = *reinterpret_cast<const float4*>(w + k4*4);
    #pragma unroll
    for (int t=0;t<16;t++){
      float4 e4 = *reinterpret_cast<const float4*>(&eL[t][k4*4]);
      acc[t] += wv.x*e4.x + wv.y*e4.y + wv.z*e4.z + wv.w*e4.w;
    }
  }
  #pragma unroll
  for (int t=0;t<16;t++) Gp[(size_t)(t0+t)*4096 + prow] = (f16)(acc[t] + base);
}

// ---- one-time: W_hh -> f16 permuted rows ----
__global__ void k_cvt_whh(const float* __restrict__ W, f16* __restrict__ out){
  int r = blockIdx.x;
  int g = r >> 10, j = r & 1023;
  int prow = (j>>5)*128 + g*32 + (j&31);
  int k0 = threadIdx.x*8;
  float4 a = *reinterpret_cast<const float4*>(W + (size_t)r*HID + k0);
  float4 c = *reinterpret_cast<const float4*>(W + (size_t)r*HID + k0 + 4);
  f16x8 v = { (f16)a.x,(f16)a.y,(f16)a.z,(f16)a.w,(f16)c.x,(f16)c.y,(f16)c.z,(f16)c.w };
  *reinterpret_cast<f16x8*>(out + (size_t)prow*HID + k0) = v;
}
// ---- one-time: Wa_h -> f16 ----
__global__ void k_cvt_wah(const float* __restrict__ W, f16* __restrict__ out){
  int r = blockIdx.x;
  int k0 = threadIdx.x*8;
  float4 a = *reinterpret_cast<const float4*>(W + (size_t)r*HID + k0);
  float4 c = *reinterpret_cast<const float4*>(W + (size_t)r*HID + k0 + 4);
  f16x8 v = { (f16)a.x,(f16)a.y,(f16)a.z,(f16)a.w,(f16)c.x,(f16)c.y,(f16)c.z,(f16)c.w };
  *reinterpret_cast<f16x8*>(out + (size_t)r*HID + k0) = v;
}

// ---- one-time: Vt[prow][s] = Wihc[prow]·enc[s] via bf16 MFMA (grid 8 x 32) ----
__global__ __launch_bounds__(256) void k_gemmV(const float* __restrict__ W_ih,
                                               const float* __restrict__ enc,
                                               f16* __restrict__ Vt){
  int bn = blockIdx.x, bm = blockIdx.y;
  int tid = threadIdx.x;
  int wid = tid>>6, lane = tid&63;
  int wr = wid>>1, wc = wid&1;
  int rowf = lane&15, kg = lane>>4;
  const int m_base = bm*128 + wr*64;
  const int n_base = bn*128 + wc*64;
  const float* Ap[4];
  #pragma unroll
  for (int mt=0;mt<4;mt++){
    int prow = m_base + mt*16 + rowf;
    int blk = prow>>7, g = (prow>>5)&3, jl = prow&31;   // inverse perm
    int r = g*HID + blk*32 + jl;
    Ap[mt] = W_ih + (size_t)r*(EMBED+ENCD) + EMBED + kg*8;
  }
  const float* Bp = enc + (size_t)(n_base + rowf)*ENCD + kg*8;
  f32x4 acc[4][4];
  #pragma unroll
  for (int i=0;i<4;i++)
    #pragma unroll
    for (int jv=0;jv<4;jv++) acc[i][jv] = (f32x4){0.f,0.f,0.f,0.f};
  for (int kk=0; kk<ENCD; kk+=32){
    bf16x8v av[4], bv[4];
    #pragma unroll
    for (int mt=0;mt<4;mt++) av[mt] = cvt8(Ap[mt] + kk);
    #pragma unroll
    for (int nt=0;nt<4;nt++) bv[nt] = cvt8(Bp + (size_t)nt*16*ENCD + kk);
    #pragma unroll
    for (int mt=0;mt<4;mt++)
      #pragma unroll
      for (int nt=0;nt<4;nt++)
        acc[mt][nt] = __builtin_amdgcn_mfma_f32_16x16x32_bf16(av[mt], bv[nt], acc[mt][nt], 0,0,0);
  }
  #pragma unroll
  for (int mt=0;mt<4;mt++){
    #pragma unroll
    for (int nt=0;nt<4;nt++){
      int n = n_base + nt*16 + rowf;
      #pragma unroll
      for (int i=0;i<4;i++){
        int m = m_base + mt*16 + kg*4 + i;
        Vt[(size_t)m*SRC + n] = (f16)acc[mt][nt][i];
      }
    }
  }
}

// ---- one-time: Hh[0]=h0, Cc=c0 (grid 8 x 128) ----
__global__ void k_prep0(const float* __restrict__ h0, const float* __restrict__ c0,
                        float* __restrict__ Hh, float* __restrict__ Cc){
  int i = blockIdx.x*128 + threadIdx.x;
  Hh[i] = h0[i];
  Cc[i] = c0[i];
}

// ---- per step: ONE kernel, 32 blocks x 1024 thr, NO cross-block sync ----
__global__ __launch_bounds__(1024) void k_one(int t,
    const f16* __restrict__ Tt, const f16* __restrict__ Wah_h,
    const f16* __restrict__ Whh_h, const f16* __restrict__ Vt,
    const f16* __restrict__ Gp, const float* __restrict__ v_a,
    float* __restrict__ Hh, float* __restrict__ Cc, float* __restrict__ Pout)
{
  const int b = blockIdx.x, tid = threadIdx.x;
  __shared__ f16x2 hs2[512];        // h_t f16 pairs
  __shared__ float vas[128];
  __shared__ float wah[128];
  __shared__ float twl[128];        // tanh(wah)
  __shared__ float psl[1024];       // unnormalized p (identical across blocks)
  __shared__ f16x2 ps2h[512];       // normalized p as f16 pairs
  __shared__ float g2[128];
  __shared__ float invs;

  const int l8 = tid >> 3, q8 = tid & 7;

  // A0: load h_t (launch-boundary coherent) + v_a
  if (tid < 256){
    float4 v0 = *reinterpret_cast<const float4*>(Hh + (size_t)t*HID + tid*4);
    hs2[tid*2]   = (f16x2){(f16)v0.x,(f16)v0.y};
    hs2[tid*2+1] = (f16x2){(f16)v0.z,(f16)v0.w};
  } else if (tid < 384){
    vas[tid-256] = v_a[tid-256];
  }
  __syncthreads();
  // A1: wah = Wa_h·h  (redundant per block; 128 rows x 8 lanes)
  {
    const f16x8* wr = (const f16x8*)(Wah_h + (size_t)l8*HID + q8*128);
    float acc = 0.f;
    #pragma unroll
    for (int i = 0; i < 16; ++i){
      f16x8 wv = wr[i];
      const f16x2* wp = (const f16x2*)&wv;
      int k2 = q8*64 + i*4;
      acc = __builtin_amdgcn_fdot2(wp[0], hs2[k2+0], acc, false);
      acc = __builtin_amdgcn_fdot2(wp[1], hs2[k2+1], acc, false);
      acc = __builtin_amdgcn_fdot2(wp[2], hs2[k2+2], acc, false);
      acc = __builtin_amdgcn_fdot2(wp[3], hs2[k2+3], acc, false);
    }
    acc += __shfl_xor(acc,1); acc += __shfl_xor(acc,2); acc += __shfl_xor(acc,4);
    if (q8 == 0) wah[l8] = acc;
  }
  __syncthreads();
  // A2: tw = tanh(wah)
  if (tid < 128) twl[tid] = tanh_f(wah[tid]);
  __syncthreads();
  // A3: scores for ALL 1024 rows (1 row/thread) via tanh identity
  {
    const f16x8* Tp = (const f16x8*)(Tt + (size_t)tid*ATTN);
    float sc = 0.f;
    #pragma unroll
    for (int i = 0; i < 16; ++i){
      f16x8 tv = Tp[i];
      #pragma unroll
      for (int u = 0; u < 8; ++u){
        int a = i*8 + u;
        float T = (float)tv[u];
        float w = twl[a];
        float num = T + w;
        float den = fmaf(T, w, 1.f);
        sc += vas[a] * num * __builtin_amdgcn_rcpf(den);
      }
    }
    psl[tid] = __expf(sc);
  }
  __syncthreads();
  // A4: den reduce (wave 0)
  if (tid < 64){
    float acc = 0.f;
    #pragma unroll
    for (int k = 0; k < 16; ++k) acc += psl[tid + 64*k];
    acc += __shfl_xor(acc,1); acc += __shfl_xor(acc,2); acc += __shfl_xor(acc,4);
    acc += __shfl_xor(acc,8); acc += __shfl_xor(acc,16); acc += __shfl_xor(acc,32);
    if (tid == 0) invs = 1.f/acc;
  }
  __syncthreads();
  // A5: pack normalized p to f16 pairs; write own attn rows
  if (tid < 512){
    float iv = invs;
    ps2h[tid] = (f16x2){ (f16)(psl[2*tid]*iv), (f16)(psl[2*tid+1]*iv) };
  } else if (tid < 544){
    int s = b*32 + (tid - 512);
    Pout[(size_t)t*SRC + s] = psl[s]*invs;
  }
  __syncthreads();
  // B1: gates = Whh·h + V·p̂ + G for this block's 128 prows
  {
    const f16x8* wA = (const f16x8*)(Whh_h + (size_t)(b*128 + l8)*HID + q8*128);
    const f16x8* wV = (const f16x8*)(Vt   + (size_t)(b*128 + l8)*SRC + q8*128);
    float acc = 0.f;
    #pragma unroll
    for (int i = 0; i < 16; ++i){
      f16x8 wv = wA[i];
      const f16x2* wp = (const f16x2*)&wv;
      int k2 = q8*64 + i*4;
      acc = __builtin_amdgcn_fdot2(wp[0], hs2[k2+0], acc, false);
      acc = __builtin_amdgcn_fdot2(wp[1], hs2[k2+1], acc, false);
      acc = __builtin_amdgcn_fdot2(wp[2], hs2[k2+2], acc, false);
      acc = __builtin_amdgcn_fdot2(wp[3], hs2[k2+3], acc, false);
    }
    #pragma unroll
    for (int i = 0; i < 16; ++i){
      f16x8 wv = wV[i];
      const f16x2* wp = (const f16x2*)&wv;
      int k2 = q8*64 + i*4;
      acc = __builtin_amdgcn_fdot2(wp[0], ps2h[k2+0], acc, false);
      acc = __builtin_amdgcn_fdot2(wp[1], ps2h[k2+1], acc, false);
      acc = __builtin_amdgcn_fdot2(wp[2], ps2h[k2+2], acc, false);
      acc = __builtin_amdgcn_fdot2(wp[3], ps2h[k2+3], acc, false);
    }
    acc += __shfl_xor(acc,1); acc += __shfl_xor(acc,2); acc += __shfl_xor(acc,4);
    if (q8 == 0) g2[l8] = acc + (float)Gp[(size_t)t*4096 + b*128 + l8];
  }
  __syncthreads();
  // B2: LSTM pointwise for own 32 j-dims
  if (tid < 32){
    int jl = b*32 + tid;
    float gi = g2[tid], gf = g2[32+tid], gg = g2[64+tid], go = g2[96+tid];
    float cn = sigm(gf)*Cc[jl] + sigm(gi)*tanh_f(gg);
    float hn = sigm(go)*tanh_f(cn);
    Cc[jl] = cn;
    Hh[(size_t)(t+1)*HID + jl] = hn;
  }
}

// ---- epilogue: logits = H @ W_out^T + b_out (bf16 MFMA, f32 in/out) ----
__global__ __launch_bounds__(256) void k_gemm(const float* __restrict__ A, const float* __restrict__ B,
                                              const float* __restrict__ bias, float* __restrict__ C){
  int bn = blockIdx.x, bm = blockIdx.y;
  int tid = threadIdx.x;
  int wid = tid>>6, lane = tid&63;
  int wr = wid>>1, wc = wid&1;
  int rowf = lane&15, kg = lane>>4;
  const int m_base = bm*128 + wr*64;
  const int n_base = bn*128 + wc*64;
  const float* Ap = A + (size_t)(m_base + rowf)*HID + kg*8;
  const float* Bp = B + (size_t)(n_base + rowf)*HID + kg*8;
  f32x4 acc[4][4];
  #pragma unroll
  for (int i=0;i<4;i++)
    #pragma unroll
    for (int jv=0;jv<4;jv++) acc[i][jv] = (f32x4){0.f,0.f,0.f,0.f};
  for (int kk=0; kk<HID; kk+=32){
    bf16x8v av[4], bv[4];
    #pragma unroll
    for (int mt=0;mt<4;mt++) av[mt] = cvt8(Ap + (size_t)mt*16*HID + kk);
    #pragma unroll
    for (int nt=0;nt<4;nt++) bv[nt] = cvt8(Bp + (size_t)nt*16*HID + kk);
    #pragma unroll
    for (int mt=0;mt<4;mt++)
      #pragma unroll
      for (int nt=0;nt<4;nt++)
        acc[mt][nt] = __builtin_amdgcn_mfma_f32_16x16x32_bf16(av[mt], bv[nt], acc[mt][nt], 0,0,0);
  }
  #pragma unroll
  for (int mt=0;mt<4;mt++){
    #pragma unroll
    for (int nt=0;nt<4;nt++){
      int n = n_base + nt*16 + rowf;
      float bo = bias[n];
      #pragma unroll
      for (int i=0;i<4;i++){
        int m = m_base + mt*16 + kg*4 + i;
        C[(size_t)m*VOCAB + n] = acc[mt][nt][i] + bo;
      }
    }
  }
}

extern "C" void kernel_launch(void* const* d_in, const int* in_sizes, int n_in,
                              void* d_out, int out_size, void* d_ws, size_t ws_size,
                              hipStream_t stream){
  const float* enc    = (const float*)d_in[0];
  const float* h0     = (const float*)d_in[1];
  const float* c0     = (const float*)d_in[2];
  const int*   sos    = (const int*)d_in[3];
  const int*   tgt    = (const int*)d_in[4];
  const float* embt   = (const float*)d_in[5];
  const float* Wa_enc = (const float*)d_in[6];
  const float* Wa_h   = (const float*)d_in[7];
  const float* v_a    = (const float*)d_in[8];
  const float* W_ih   = (const float*)d_in[9];
  const float* W_hh   = (const float*)d_in[10];
  const float* b_ih   = (const float*)d_in[11];
  const float* b_hh   = (const float*)d_in[12];
  const float* W_out  = (const float*)d_in[13];
  const float* b_out  = (const float*)d_in[14];

  float* ws   = (float*)d_ws;
  f16*   Tt   = (f16*)(ws + OFF_T);
  f16*   Gp   = (f16*)(ws + OFF_G);
  float* Hh   = ws + OFF_HH;
  float* Cc   = ws + OFF_CC;
  f16*   Wah_h= (f16*)(ws + OFF_WAH);
  f16*   Whh_h= (f16*)(ws + OFF_WHH);
  f16*   Vt   = (f16*)(ws + OFF_VT);

  float* out_logits = (float*)d_out;
  float* out_attn   = out_logits + (size_t)TGT*VOCAB;

  k_encT    <<<64, 128, 0, stream>>>(enc, Wa_enc, Tt);
  k_gbase   <<<dim3(16, 32), 256, 0, stream>>>(sos, tgt, embt, W_ih, b_ih, b_hh, Gp);
  k_cvt_whh <<<4096, 128, 0, stream>>>(W_hh, Whh_h);
  k_cvt_wah <<<128, 128, 0, stream>>>(Wa_h, Wah_h);
  k_gemmV   <<<dim3(8, 32), 256, 0, stream>>>(W_ih, enc, Vt);
  k_prep0   <<<8, 128, 0, stream>>>(h0, c0, Hh, Cc);

  for (int t = 0; t < TGT; ++t){
    k_one<<<NB, 1024, 0, stream>>>(t, Tt, Wah_h, Whh_h, Vt, Gp, v_a, Hh, Cc, out_attn);
  }

  k_gemm<<<dim3(250, 4), 256, 0, stream>>>(Hh + HID, W_out, b_out, out_logits);
}

// Round 10
// 7186.837 us; speedup vs baseline: 2.3497x; 2.3497x over previous
//
#include <hip/hip_runtime.h>
#include <hip/hip_bf16.h>

#define VOCAB 32000
#define EMBED 512
#define ENCD  512
#define HID   1024
#define ATTN  128
#define SRC   1024
#define TGT   512
#define NB    64          // blocks for the per-step kernel
#define NT    512         // threads per block

typedef __hip_bfloat16 bf16;
typedef _Float16 f16;
typedef __attribute__((ext_vector_type(2))) _Float16 f16x2;
typedef __attribute__((ext_vector_type(8))) _Float16 f16x8;
typedef __attribute__((ext_vector_type(8))) short bf16x8v;
typedef __attribute__((ext_vector_type(4))) float f32x4;

// ---- workspace layout (float offsets), 23.9 MB total ----
#define OFF_TP    0           // f16x2 [1024][128] {T, v*T}
#define OFF_G     131072      // f16 [512][4096] gate bases, prow-permuted
#define OFF_HH    1179648     // f32 [513][1024] h history
#define OFF_CC    1704960     // f32 [1024] c state
#define OFF_WAHG  1705984     // f32 [128] wah (+pad)            (atomic)
#define OFF_PB    1706240     // f32 [1024] unnorm p (+pad)      (atomic)
#define OFF_CTR   1707328     // u32 [2] counters (+pad)         (atomic)
#define OFF_WAHW  1707392     // f16 [128][1024] Wa_h
#define OFF_WHH   1772928     // f16 [4096][1024] W_hh, prow-permuted
#define OFF_VT    3870080     // f16 [4096][1024] V[prow][s]
// end = 5967232 floats = 23.9 MB

__device__ __forceinline__ float sigm(float x){ return 1.f/(1.f+__expf(-x)); }
__device__ __forceinline__ float tanh_f(float x){
  float ax = fabsf(x);
  float e = __expf(-2.f*ax);
  float r = (1.f - e) / (1.f + e);
  return copysignf(r, x);
}
__device__ __forceinline__ short f2bs(float x){
  union { bf16 h; short s; } u; u.h = __float2bfloat16(x); return u.s;
}
__device__ __forceinline__ bf16x8v cvt8(const float* p){
  float4 a = *reinterpret_cast<const float4*>(p);
  float4 b = *reinterpret_cast<const float4*>(p+4);
  bf16x8v r;
  r[0]=f2bs(a.x); r[1]=f2bs(a.y); r[2]=f2bs(a.z); r[3]=f2bs(a.w);
  r[4]=f2bs(b.x); r[5]=f2bs(b.y); r[6]=f2bs(b.z); r[7]=f2bs(b.w);
  return r;
}
__device__ __forceinline__ float aldf(const float* p){
  return __hip_atomic_load(p, __ATOMIC_RELAXED, __HIP_MEMORY_SCOPE_AGENT);
}
__device__ __forceinline__ void astf(float* p, float v){
  __hip_atomic_store(p, v, __ATOMIC_RELAXED, __HIP_MEMORY_SCOPE_AGENT);
}
__device__ __forceinline__ unsigned aldu(const unsigned* p){
  return __hip_atomic_load(p, __ATOMIC_RELAXED, __HIP_MEMORY_SCOPE_AGENT);
}

// ---- one-time: TP[s][a] = {T, v_a*T}, T = clamp(tanh(enc_proj)) (grid 64x128) ----
__global__ void k_encTP(const float* __restrict__ enc, const float* __restrict__ Wa_enc,
                        const float* __restrict__ v_a, unsigned* __restrict__ TP){
  __shared__ float eL[16][ENCD];
  int s0 = blockIdx.x*16, tid = threadIdx.x;
  #pragma unroll
  for (int i=0;i<16;i++){
    int li = tid + i*128;
    int t = li>>7, k4 = li&127;
    *reinterpret_cast<float4*>(&eL[t][k4*4]) =
      *reinterpret_cast<const float4*>(enc + (size_t)(s0+t)*ENCD + k4*4);
  }
  __syncthreads();
  const float* w = Wa_enc + (size_t)tid*ENCD;
  float va = v_a[tid];
  float acc[16];
  #pragma unroll
  for (int t=0;t<16;t++) acc[t]=0.f;
  for (int k4=0;k4<128;k4++){
    float4 wv = *reinterpret_cast<const float4*>(w + k4*4);
    #pragma unroll
    for (int t=0;t<16;t++){
      float4 e4 = *reinterpret_cast<const float4*>(&eL[t][k4*4]);
      acc[t] += wv.x*e4.x + wv.y*e4.y + wv.z*e4.z + wv.w*e4.w;
    }
  }
  #pragma unroll
  for (int t=0;t<16;t++){
    float th = tanh_f(acc[t]);
    th = fminf(0.9995f, fmaxf(-0.9995f, th));
    union { f16x2 h; unsigned u; } cv;
    cv.h = (f16x2){ (f16)th, (f16)(va*th) };
    TP[(size_t)(s0+t)*ATTN + tid] = cv.u;
  }
}

// ---- one-time: Gp[t][prow] f16, prow = (j>>4)*64 + g*16 + (j&15) ----
__global__ void k_gbase(const int* __restrict__ sos, const int* __restrict__ tgt,
                        const float* __restrict__ embt, const float* __restrict__ W_ih,
                        const float* __restrict__ b_ih, const float* __restrict__ b_hh,
                        f16* __restrict__ Gp){
  __shared__ float eL[16][EMBED];
  int tid = threadIdx.x;
  int t0 = blockIdx.y*16;
  #pragma unroll
  for (int i=0;i<8;i++){
    int li = tid + i*256;
    int t = li>>7, k4 = li&127;
    int tg = t0 + t;
    int tok = (tg==0) ? sos[0] : tgt[tg-1];
    *reinterpret_cast<float4*>(&eL[t][k4*4]) =
      *reinterpret_cast<const float4*>(embt + (size_t)tok*EMBED + k4*4);
  }
  __syncthreads();
  int r = blockIdx.x*256 + tid;
  int g = r>>10, j = r&1023;
  int prow = (j>>4)*64 + g*16 + (j&15);
  const float* w = W_ih + (size_t)r*(EMBED+ENCD);
  float base = b_ih[r] + b_hh[r];
  float acc[16];
  #pragma unroll
  for (int t=0;t<16;t++) acc[t]=0.f;
  for (int k4=0;k4<128;k4++){
    float4 wv = *reinterpret_cast<const float4*>(w + k4*4);
    #pragma unroll
    for (int t=0;t<16;t++){
      float4 e4 = *reinterpret_cast<const float4*>(&eL[t][k4*4]);
      acc[t] += wv.x*e4.x + wv.y*e4.y + wv.z*e4.z + wv.w*e4.w;
    }
  }
  #pragma unroll
  for (int t=0;t<16;t++) Gp[(size_t)(t0+t)*4096 + prow] = (f16)(acc[t] + base);
}

// ---- one-time: W_hh -> f16 permuted rows ----
__global__ void k_cvt_whh(const float* __restrict__ W, f16* __restrict__ out){
  int r = blockIdx.x;
  int g = r >> 10, j = r & 1023;
  int prow = (j>>4)*64 + g*16 + (j&15);
  int k0 = threadIdx.x*8;
  float4 a = *reinterpret_cast<const float4*>(W + (size_t)r*HID + k0);
  float4 c = *reinterpret_cast<const float4*>(W + (size_t)r*HID + k0 + 4);
  f16x8 v = { (f16)a.x,(f16)a.y,(f16)a.z,(f16)a.w,(f16)c.x,(f16)c.y,(f16)c.z,(f16)c.w };
  *reinterpret_cast<f16x8*>(out + (size_t)prow*HID + k0) = v;
}
// ---- one-time: Wa_h -> f16 ----
__global__ void k_cvt_wah(const float* __restrict__ W, f16* __restrict__ out){
  int r = blockIdx.x;
  int k0 = threadIdx.x*8;
  float4 a = *reinterpret_cast<const float4*>(W + (size_t)r*HID + k0);
  float4 c = *reinterpret_cast<const float4*>(W + (size_t)r*HID + k0 + 4);
  f16x8 v = { (f16)a.x,(f16)a.y,(f16)a.z,(f16)a.w,(f16)c.x,(f16)c.y,(f16)c.z,(f16)c.w };
  *reinterpret_cast<f16x8*>(out + (size_t)r*HID + k0) = v;
}

// ---- one-time: Vt[prow][s] = Wihc[prow]·enc[s] via bf16 MFMA (grid 8 x 32) ----
__global__ __launch_bounds__(256) void k_gemmV(const float* __restrict__ W_ih,
                                               const float* __restrict__ enc,
                                               f16* __restrict__ Vt){
  int bn = blockIdx.x, bm = blockIdx.y;
  int tid = threadIdx.x;
  int wid = tid>>6, lane = tid&63;
  int wr = wid>>1, wc = wid&1;
  int rowf = lane&15, kg = lane>>4;
  const int m_base = bm*128 + wr*64;
  const int n_base = bn*128 + wc*64;
  const float* Ap[4];
  #pragma unroll
  for (int mt=0;mt<4;mt++){
    int prow = m_base + mt*16 + rowf;
    int bb = prow>>6, g = (prow>>4)&3, jl = prow&15;   // inverse perm
    int r = g*HID + bb*16 + jl;
    Ap[mt] = W_ih + (size_t)r*(EMBED+ENCD) + EMBED + kg*8;
  }
  const float* Bp = enc + (size_t)(n_base + rowf)*ENCD + kg*8;
  f32x4 acc[4][4];
  #pragma unroll
  for (int i=0;i<4;i++)
    #pragma unroll
    for (int jv=0;jv<4;jv++) acc[i][jv] = (f32x4){0.f,0.f,0.f,0.f};
  for (int kk=0; kk<ENCD; kk+=32){
    bf16x8v av[4], bv[4];
    #pragma unroll
    for (int mt=0;mt<4;mt++) av[mt] = cvt8(Ap[mt] + kk);
    #pragma unroll
    for (int nt=0;nt<4;nt++) bv[nt] = cvt8(Bp + (size_t)nt*16*ENCD + kk);
    #pragma unroll
    for (int mt=0;mt<4;mt++)
      #pragma unroll
      for (int nt=0;nt<4;nt++)
        acc[mt][nt] = __builtin_amdgcn_mfma_f32_16x16x32_bf16(av[mt], bv[nt], acc[mt][nt], 0,0,0);
  }
  #pragma unroll
  for (int mt=0;mt<4;mt++){
    #pragma unroll
    for (int nt=0;nt<4;nt++){
      int n = n_base + nt*16 + rowf;
      #pragma unroll
      for (int i=0;i<4;i++){
        int m = m_base + mt*16 + kg*4 + i;
        Vt[(size_t)m*SRC + n] = (f16)acc[mt][nt][i];
      }
    }
  }
}

// ---- one-time: Hh[0]=h0, Cc=c0, counters=0 (grid 8 x 128) ----
__global__ void k_prep0(const float* __restrict__ h0, const float* __restrict__ c0,
                        float* __restrict__ Hh, float* __restrict__ Cc,
                        unsigned* __restrict__ ctr){
  int b = blockIdx.x, tid = threadIdx.x;
  int i = b*128 + tid;
  Hh[i] = h0[i];
  Cc[i] = c0[i];
  if (b == 0 && tid < 2) ctr[tid] = 0u;
}

// ---- per step: ONE kernel, 64 blocks x 512 thr; syncs hidden behind matvecs ----
__global__ __launch_bounds__(NT) void k_one(int t,
    const unsigned* __restrict__ TP, const f16* __restrict__ Wah_h,
    const f16* __restrict__ Whh_h, const f16* __restrict__ Vt,
    const f16* __restrict__ Gp, const float* __restrict__ v_a,
    float* __restrict__ Hh, float* __restrict__ Cc,
    float* __restrict__ wahg, float* __restrict__ pbuf,
    unsigned* __restrict__ ctr, float* __restrict__ Pout)
{
  const int b = blockIdx.x, tid = threadIdx.x;
  __shared__ f16x8 hs8[128];       // h_t packed
  __shared__ f16x8 ps8[128];       // normalized p packed
  __shared__ float2 vwp[128];      // {tanh(wah), v*tanh(wah)}
  __shared__ float gacc[64];
  __shared__ float g2[64];
  __shared__ float pown[16];
  __shared__ float wpart[8];
  __shared__ float invs;

  const int l8 = tid >> 3, q8 = tid & 7;
  const unsigned tgt_c = 64u*(unsigned)(t+1);

  // P0: load h_t (launch-boundary coherent), pack f16x8
  if (tid < 128){
    float4 a = *reinterpret_cast<const float4*>(Hh + (size_t)t*HID + tid*8);
    float4 c = *reinterpret_cast<const float4*>(Hh + (size_t)t*HID + tid*8 + 4);
    hs8[tid] = (f16x8){ (f16)a.x,(f16)a.y,(f16)a.z,(f16)a.w,
                        (f16)c.x,(f16)c.y,(f16)c.z,(f16)c.w };
  }
  __syncthreads();
  // P1: produce wah dims {2b, 2b+1} (2 waves)
  if (tid < 128){
    int w = tid >> 6, lane = tid & 63;
    const f16x8* wr = (const f16x8*)(Wah_h + (size_t)(2*b+w)*HID) + lane;
    float acc = 0.f;
    #pragma unroll
    for (int i = 0; i < 2; ++i){
      f16x8 wv = wr[i*64];
      f16x8 hv = hs8[lane + i*64];
      const f16x2* wp = (const f16x2*)&wv;
      const f16x2* hp = (const f16x2*)&hv;
      acc = __builtin_amdgcn_fdot2(wp[0], hp[0], acc, false);
      acc = __builtin_amdgcn_fdot2(wp[1], hp[1], acc, false);
      acc = __builtin_amdgcn_fdot2(wp[2], hp[2], acc, false);
      acc = __builtin_amdgcn_fdot2(wp[3], hp[3], acc, false);
    }
    acc += __shfl_xor(acc,1); acc += __shfl_xor(acc,2); acc += __shfl_xor(acc,4);
    acc += __shfl_xor(acc,8); acc += __shfl_xor(acc,16); acc += __shfl_xor(acc,32);
    if (lane == 0) astf(&wahg[2*b + w], acc);
  }
  __syncthreads();                                  // drain wah stores
  if (tid == 0)
    __hip_atomic_fetch_add(&ctr[0], 1u, __ATOMIC_RELAXED, __HIP_MEMORY_SCOPE_AGENT);
  // P2: gacc = Whh·h own 64 rows (hides c1 + wah flight)
  {
    const f16x8* wr = (const f16x8*)(Whh_h + (size_t)(b*64 + l8)*HID + q8*128);
    float acc = 0.f;
    #pragma unroll
    for (int i = 0; i < 16; ++i){
      f16x8 wv = wr[i];
      f16x8 hv = hs8[q8*16 + i];
      const f16x2* wp = (const f16x2*)&wv;
      const f16x2* hp = (const f16x2*)&hv;
      acc = __builtin_amdgcn_fdot2(wp[0], hp[0], acc, false);
      acc = __builtin_amdgcn_fdot2(wp[1], hp[1], acc, false);
      acc = __builtin_amdgcn_fdot2(wp[2], hp[2], acc, false);
      acc = __builtin_amdgcn_fdot2(wp[3], hp[3], acc, false);
    }
    acc += __shfl_xor(acc,1); acc += __shfl_xor(acc,2); acc += __shfl_xor(acc,4);
    if (q8 == 0) gacc[l8] = acc;
  }
  // P3: poll c1 (should be satisfied), build vwp
  if (tid == 0){
    while (aldu(&ctr[0]) < tgt_c) __builtin_amdgcn_s_sleep(1);
  }
  __syncthreads();
  if (tid < 128){
    float w = aldf(&wahg[tid]);
    float tw = tanh_f(w);
    vwp[tid] = make_float2(tw, v_a[tid]*tw);
  }
  __syncthreads();
  // P4: scores for own 16 s-rows (16 rows x 32 lanes x 4 a-dims)
  {
    int row = tid >> 5, l5 = tid & 31;
    const f16x8* tp8 = (const f16x8*)((const f16*)TP + ((size_t)(b*16+row)*ATTN + l5*4)*2);
    f16x8 tv = tp8[0];
    float sc = 0.f;
    #pragma unroll
    for (int u = 0; u < 4; ++u){
      float T  = (float)tv[2*u];
      float vT = (float)tv[2*u+1];
      float2 vw = vwp[l5*4 + u];
      float num = vT + vw.y;
      float den = fmaf(T, vw.x, 1.f);
      sc = fmaf(num, __builtin_amdgcn_rcpf(den), sc);
    }
    sc += __shfl_xor(sc,1); sc += __shfl_xor(sc,2); sc += __shfl_xor(sc,4);
    sc += __shfl_xor(sc,8); sc += __shfl_xor(sc,16);
    if (l5 == 0){
      float pv = __expf(sc);
      pown[row] = pv;
      astf(&pbuf[b*16 + row], pv);
    }
  }
  __syncthreads();                                  // drain p stores
  if (tid == 0)
    __hip_atomic_fetch_add(&ctr[1], 1u, __ATOMIC_RELAXED, __HIP_MEMORY_SCOPE_AGENT);
  // P5: poll c2 (~skew only), read all p, normalize, pack
  if (tid == 0){
    while (aldu(&ctr[1]) < tgt_c) __builtin_amdgcn_s_sleep(1);
  }
  __syncthreads();
  {
    float p0 = aldf(&pbuf[2*tid]);
    float p1 = aldf(&pbuf[2*tid+1]);
    float s2 = p0 + p1;
    s2 += __shfl_xor(s2,1); s2 += __shfl_xor(s2,2); s2 += __shfl_xor(s2,4);
    s2 += __shfl_xor(s2,8); s2 += __shfl_xor(s2,16); s2 += __shfl_xor(s2,32);
    if ((tid & 63) == 0) wpart[tid >> 6] = s2;
    __syncthreads();
    if (tid == 0){
      float d = 0.f;
      #pragma unroll
      for (int k = 0; k < 8; ++k) d += wpart[k];
      invs = 1.f/d;
    }
    __syncthreads();
    float iv = invs;
    ((f16x2*)ps8)[tid] = (f16x2){ (f16)(p0*iv), (f16)(p1*iv) };
    if (tid < 16) Pout[(size_t)t*SRC + b*16 + tid] = pown[tid]*iv;   // final attn rows
  }
  __syncthreads();
  // P6: gates = gacc + V·p̂ + G for own 64 rows
  {
    const f16x8* wr = (const f16x8*)(Vt + (size_t)(b*64 + l8)*SRC + q8*128);
    float acc = 0.f;
    #pragma unroll
    for (int i = 0; i < 16; ++i){
      f16x8 wv = wr[i];
      f16x8 pv = ps8[q8*16 + i];
      const f16x2* wp = (const f16x2*)&wv;
      const f16x2* pp = (const f16x2*)&pv;
      acc = __builtin_amdgcn_fdot2(wp[0], pp[0], acc, false);
      acc = __builtin_amdgcn_fdot2(wp[1], pp[1], acc, false);
      acc = __builtin_amdgcn_fdot2(wp[2], pp[2], acc, false);
      acc = __builtin_amdgcn_fdot2(wp[3], pp[3], acc, false);
    }
    acc += __shfl_xor(acc,1); acc += __shfl_xor(acc,2); acc += __shfl_xor(acc,4);
    if (q8 == 0) g2[l8] = acc + gacc[l8] + (float)Gp[(size_t)t*4096 + b*64 + l8];
  }
  __syncthreads();
  // P7: LSTM pointwise for own 16 j-dims
  if (tid < 16){
    int jl = b*16 + tid;
    float gi = g2[tid], gf = g2[16+tid], gg = g2[32+tid], go = g2[48+tid];
    float cn = sigm(gf)*Cc[jl] + sigm(gi)*tanh_f(gg);
    float hn = sigm(go)*tanh_f(cn);
    Cc[jl] = cn;
    Hh[(size_t)(t+1)*HID + jl] = hn;
  }
}

// ---- epilogue: logits = H @ W_out^T + b_out (bf16 MFMA, f32 in/out) ----
__global__ __launch_bounds__(256) void k_gemm(const float* __restrict__ A, const float* __restrict__ B,
                                              const float* __restrict__ bias, float* __restrict__ C){
  int bn = blockIdx.x, bm = blockIdx.y;
  int tid = threadIdx.x;
  int wid = tid>>6, lane = tid&63;
  int wr = wid>>1, wc = wid&1;
  int rowf = lane&15, kg = lane>>4;
  const int m_base = bm*128 + wr*64;
  const int n_base = bn*128 + wc*64;
  const float* Ap = A + (size_t)(m_base + rowf)*HID + kg*8;
  const float* Bp = B + (size_t)(n_base + rowf)*HID + kg*8;
  f32x4 acc[4][4];
  #pragma unroll
  for (int i=0;i<4;i++)
    #pragma unroll
    for (int jv=0;jv<4;jv++) acc[i][jv] = (f32x4){0.f,0.f,0.f,0.f};
  for (int kk=0; kk<HID; kk+=32){
    bf16x8v av[4], bv[4];
    #pragma unroll
    for (int mt=0;mt<4;mt++) av[mt] = cvt8(Ap + (size_t)mt*16*HID + kk);
    #pragma unroll
    for (int nt=0;nt<4;nt++) bv[nt] = cvt8(Bp + (size_t)nt*16*HID + kk);
    #pragma unroll
    for (int mt=0;mt<4;mt++)
      #pragma unroll
      for (int nt=0;nt<4;nt++)
        acc[mt][nt] = __builtin_amdgcn_mfma_f32_16x16x32_bf16(av[mt], bv[nt], acc[mt][nt], 0,0,0);
  }
  #pragma unroll
  for (int mt=0;mt<4;mt++){
    #pragma unroll
    for (int nt=0;nt<4;nt++){
      int n = n_base + nt*16 + rowf;
      float bo = bias[n];
      #pragma unroll
      for (int i=0;i<4;i++){
        int m = m_base + mt*16 + kg*4 + i;
        C[(size_t)m*VOCAB + n] = acc[mt][nt][i] + bo;
      }
    }
  }
}

extern "C" void kernel_launch(void* const* d_in, const int* in_sizes, int n_in,
                              void* d_out, int out_size, void* d_ws, size_t ws_size,
                              hipStream_t stream){
  const float* enc    = (const float*)d_in[0];
  const float* h0     = (const float*)d_in[1];
  const float* c0     = (const float*)d_in[2];
  const int*   sos    = (const int*)d_in[3];
  const int*   tgt    = (const int*)d_in[4];
  const float* embt   = (const float*)d_in[5];
  const float* Wa_enc = (const float*)d_in[6];
  const float* Wa_h   = (const float*)d_in[7];
  const float* v_a    = (const float*)d_in[8];
  const float* W_ih   = (const float*)d_in[9];
  const float* W_hh   = (const float*)d_in[10];
  const float* b_ih   = (const float*)d_in[11];
  const float* b_hh   = (const float*)d_in[12];
  const float* W_out  = (const float*)d_in[13];
  const float* b_out  = (const float*)d_in[14];

  float* ws   = (float*)d_ws;
  unsigned* TP = (unsigned*)(ws + OFF_TP);
  f16*   Gp   = (f16*)(ws + OFF_G);
  float* Hh   = ws + OFF_HH;
  float* Cc   = ws + OFF_CC;
  float* wahg = ws + OFF_WAHG;
  float* pbuf = ws + OFF_PB;
  unsigned* ctr = (unsigned*)(ws + OFF_CTR);
  f16*   Wah_h= (f16*)(ws + OFF_WAHW);
  f16*   Whh_h= (f16*)(ws + OFF_WHH);
  f16*   Vt   = (f16*)(ws + OFF_VT);

  float* out_logits = (float*)d_out;
  float* out_attn   = out_logits + (size_t)TGT*VOCAB;

  k_encTP   <<<64, 128, 0, stream>>>(enc, Wa_enc, v_a, TP);
  k_gbase   <<<dim3(16, 32), 256, 0, stream>>>(sos, tgt, embt, W_ih, b_ih, b_hh, Gp);
  k_cvt_whh <<<4096, 128, 0, stream>>>(W_hh, Whh_h);
  k_cvt_wah <<<128, 128, 0, stream>>>(Wa_h, Wah_h);
  k_gemmV   <<<dim3(8, 32), 256, 0, stream>>>(W_ih, enc, Vt);
  k_prep0   <<<8, 128, 0, stream>>>(h0, c0, Hh, Cc, ctr);

  for (int t = 0; t < TGT; ++t){
    k_one<<<NB, NT, 0, stream>>>(t, TP, Wah_h, Whh_h, Vt, Gp, v_a,
                                 Hh, Cc, wahg, pbuf, ctr, out_attn);
  }

  k_gemm<<<dim3(250, 4), 256, 0, stream>>>(Hh + HID, W_out, b_out, out_logits);
}

// Round 11
// 4217.151 us; speedup vs baseline: 4.0044x; 1.7042x over previous
//
#include <hip/hip_runtime.h>
#include <hip/hip_bf16.h>

#define VOCAB 32000
#define EMBED 512
#define ENCD  512
#define HID   1024
#define ATTN  128
#define SRC   1024
#define TGT   512
#define NB    64          // blocks for the per-step kernel
#define NT    512         // threads per block
#define CHUNK 16          // steps per launch

typedef __hip_bfloat16 bf16;
typedef _Float16 f16;
typedef __attribute__((ext_vector_type(2))) _Float16 f16x2;
typedef __attribute__((ext_vector_type(8))) _Float16 f16x8;
typedef __attribute__((ext_vector_type(8))) short bf16x8v;
typedef __attribute__((ext_vector_type(4))) float f32x4;

// ---- workspace layout (float offsets), ~23.9 MB total ----
#define OFF_TP    0           // u32 [1024][128] {T, v*T} f16 pairs
#define OFF_G     131072      // f16 [512][4096] gate bases, prow-permuted
#define OFF_HH    1179648     // f32 [513][1024] h history (for k_gemm)
#define OFF_CC    1704960     // f32 [1024] c state
#define OFF_WAHG  1705984     // f32 [2][128] wah double-buffered   (atomic)
#define OFF_PB    1706240     // f32 [2][1024] unnorm p dbuf        (atomic)
#define OFF_HBUF  1708288     // u32 [2][512] h packed f16x2 dbuf   (atomic)
#define OFF_CTR   1709312     // u32 [3] counters (+pad)            (atomic)
#define OFF_WAHW  1709376     // f16 [128][1024] Wa_h
#define OFF_WHH   1774912     // f16 [4096][1024] W_hh, prow-permuted
#define OFF_VT    3872064     // f16 [4096][1024] V[prow][s]
// end = 5969216 floats ≈ 23.9 MB

__device__ __forceinline__ float sigm(float x){ return 1.f/(1.f+__expf(-x)); }
__device__ __forceinline__ float tanh_f(float x){
  float ax = fabsf(x);
  float e = __expf(-2.f*ax);
  float r = (1.f - e) / (1.f + e);
  return copysignf(r, x);
}
__device__ __forceinline__ short f2bs(float x){
  union { bf16 h; short s; } u; u.h = __float2bfloat16(x); return u.s;
}
__device__ __forceinline__ bf16x8v cvt8(const float* p){
  float4 a = *reinterpret_cast<const float4*>(p);
  float4 b = *reinterpret_cast<const float4*>(p+4);
  bf16x8v r;
  r[0]=f2bs(a.x); r[1]=f2bs(a.y); r[2]=f2bs(a.z); r[3]=f2bs(a.w);
  r[4]=f2bs(b.x); r[5]=f2bs(b.y); r[6]=f2bs(b.z); r[7]=f2bs(b.w);
  return r;
}
__device__ __forceinline__ float aldf(const float* p){
  return __hip_atomic_load(p, __ATOMIC_RELAXED, __HIP_MEMORY_SCOPE_AGENT);
}
__device__ __forceinline__ void astf(float* p, float v){
  __hip_atomic_store(p, v, __ATOMIC_RELAXED, __HIP_MEMORY_SCOPE_AGENT);
}
__device__ __forceinline__ unsigned aldu(const unsigned* p){
  return __hip_atomic_load(p, __ATOMIC_RELAXED, __HIP_MEMORY_SCOPE_AGENT);
}
__device__ __forceinline__ void astu(unsigned* p, unsigned v){
  __hip_atomic_store(p, v, __ATOMIC_RELAXED, __HIP_MEMORY_SCOPE_AGENT);
}

// ---- one-time: TP[s][a] = {T, v_a*T}, T = clamp(tanh(enc_proj)) (grid 64x128) ----
__global__ void k_encTP(const float* __restrict__ enc, const float* __restrict__ Wa_enc,
                        const float* __restrict__ v_a, unsigned* __restrict__ TP){
  __shared__ float eL[16][ENCD];
  int s0 = blockIdx.x*16, tid = threadIdx.x;
  #pragma unroll
  for (int i=0;i<16;i++){
    int li = tid + i*128;
    int t = li>>7, k4 = li&127;
    *reinterpret_cast<float4*>(&eL[t][k4*4]) =
      *reinterpret_cast<const float4*>(enc + (size_t)(s0+t)*ENCD + k4*4);
  }
  __syncthreads();
  const float* w = Wa_enc + (size_t)tid*ENCD;
  float va = v_a[tid];
  float acc[16];
  #pragma unroll
  for (int t=0;t<16;t++) acc[t]=0.f;
  for (int k4=0;k4<128;k4++){
    float4 wv = *reinterpret_cast<const float4*>(w + k4*4);
    #pragma unroll
    for (int t=0;t<16;t++){
      float4 e4 = *reinterpret_cast<const float4*>(&eL[t][k4*4]);
      acc[t] += wv.x*e4.x + wv.y*e4.y + wv.z*e4.z + wv.w*e4.w;
    }
  }
  #pragma unroll
  for (int t=0;t<16;t++){
    float th = tanh_f(acc[t]);
    th = fminf(0.9995f, fmaxf(-0.9995f, th));
    union { f16x2 h; unsigned u; } cv;
    cv.h = (f16x2){ (f16)th, (f16)(va*th) };
    TP[(size_t)(s0+t)*ATTN + tid] = cv.u;
  }
}

// ---- one-time: Gp[t][prow] f16, prow = (j>>4)*64 + g*16 + (j&15) ----
__global__ void k_gbase(const int* __restrict__ sos, const int* __restrict__ tgt,
                        const float* __restrict__ embt, const float* __restrict__ W_ih,
                        const float* __restrict__ b_ih, const float* __restrict__ b_hh,
                        f16* __restrict__ Gp){
  __shared__ float eL[16][EMBED];
  int tid = threadIdx.x;
  int t0 = blockIdx.y*16;
  #pragma unroll
  for (int i=0;i<8;i++){
    int li = tid + i*256;
    int t = li>>7, k4 = li&127;
    int tg = t0 + t;
    int tok = (tg==0) ? sos[0] : tgt[tg-1];
    *reinterpret_cast<float4*>(&eL[t][k4*4]) =
      *reinterpret_cast<const float4*>(embt + (size_t)tok*EMBED + k4*4);
  }
  __syncthreads();
  int r = blockIdx.x*256 + tid;
  int g = r>>10, j = r&1023;
  int prow = (j>>4)*64 + g*16 + (j&15);
  const float* w = W_ih + (size_t)r*(EMBED+ENCD);
  float base = b_ih[r] + b_hh[r];
  float acc[16];
  #pragma unroll
  for (int t=0;t<16;t++) acc[t]=0.f;
  for (int k4=0;k4<128;k4++){
    float4 wv = *reinterpret_cast<const float4*>(w + k4*4);
    #pragma unroll
    for (int t=0;t<16;t++){
      float4 e4 = *reinterpret_cast<const float4*>(&eL[t][k4*4]);
      acc[t] += wv.x*e4.x + wv.y*e4.y + wv.z*e4.z + wv.w*e4.w;
    }
  }
  #pragma unroll
  for (int t=0;t<16;t++) Gp[(size_t)(t0+t)*4096 + prow] = (f16)(acc[t] + base);
}

// ---- one-time: W_hh -> f16 permuted rows ----
__global__ void k_cvt_whh(const float* __restrict__ W, f16* __restrict__ out){
  int r = blockIdx.x;
  int g = r >> 10, j = r & 1023;
  int prow = (j>>4)*64 + g*16 + (j&15);
  int k0 = threadIdx.x*8;
  float4 a = *reinterpret_cast<const float4*>(W + (size_t)r*HID + k0);
  float4 c = *reinterpret_cast<const float4*>(W + (size_t)r*HID + k0 + 4);
  f16x8 v = { (f16)a.x,(f16)a.y,(f16)a.z,(f16)a.w,(f16)c.x,(f16)c.y,(f16)c.z,(f16)c.w };
  *reinterpret_cast<f16x8*>(out + (size_t)prow*HID + k0) = v;
}
// ---- one-time: Wa_h -> f16 ----
__global__ void k_cvt_wah(const float* __restrict__ W, f16* __restrict__ out){
  int r = blockIdx.x;
  int k0 = threadIdx.x*8;
  float4 a = *reinterpret_cast<const float4*>(W + (size_t)r*HID + k0);
  float4 c = *reinterpret_cast<const float4*>(W + (size_t)r*HID + k0 + 4);
  f16x8 v = { (f16)a.x,(f16)a.y,(f16)a.z,(f16)a.w,(f16)c.x,(f16)c.y,(f16)c.z,(f16)c.w };
  *reinterpret_cast<f16x8*>(out + (size_t)r*HID + k0) = v;
}

// ---- one-time: Vt[prow][s] = Wihc[prow]·enc[s] via bf16 MFMA (grid 8 x 32) ----
__global__ __launch_bounds__(256) void k_gemmV(const float* __restrict__ W_ih,
                                               const float* __restrict__ enc,
                                               f16* __restrict__ Vt){
  int bn = blockIdx.x, bm = blockIdx.y;
  int tid = threadIdx.x;
  int wid = tid>>6, lane = tid&63;
  int wr = wid>>1, wc = wid&1;
  int rowf = lane&15, kg = lane>>4;
  const int m_base = bm*128 + wr*64;
  const int n_base = bn*128 + wc*64;
  const float* Ap[4];
  #pragma unroll
  for (int mt=0;mt<4;mt++){
    int prow = m_base + mt*16 + rowf;
    int bb = prow>>6, g = (prow>>4)&3, jl = prow&15;   // inverse perm
    int r = g*HID + bb*16 + jl;
    Ap[mt] = W_ih + (size_t)r*(EMBED+ENCD) + EMBED + kg*8;
  }
  const float* Bp = enc + (size_t)(n_base + rowf)*ENCD + kg*8;
  f32x4 acc[4][4];
  #pragma unroll
  for (int i=0;i<4;i++)
    #pragma unroll
    for (int jv=0;jv<4;jv++) acc[i][jv] = (f32x4){0.f,0.f,0.f,0.f};
  for (int kk=0; kk<ENCD; kk+=32){
    bf16x8v av[4], bv[4];
    #pragma unroll
    for (int mt=0;mt<4;mt++) av[mt] = cvt8(Ap[mt] + kk);
    #pragma unroll
    for (int nt=0;nt<4;nt++) bv[nt] = cvt8(Bp + (size_t)nt*16*ENCD + kk);
    #pragma unroll
    for (int mt=0;mt<4;mt++)
      #pragma unroll
      for (int nt=0;nt<4;nt++)
        acc[mt][nt] = __builtin_amdgcn_mfma_f32_16x16x32_bf16(av[mt], bv[nt], acc[mt][nt], 0,0,0);
  }
  #pragma unroll
  for (int mt=0;mt<4;mt++){
    #pragma unroll
    for (int nt=0;nt<4;nt++){
      int n = n_base + nt*16 + rowf;
      #pragma unroll
      for (int i=0;i<4;i++){
        int m = m_base + mt*16 + kg*4 + i;
        Vt[(size_t)m*SRC + n] = (f16)acc[mt][nt][i];
      }
    }
  }
}

// ---- one-time: Hh[0]=h0, Cc=c0, hbuf[0]=pack(h0), counters=0 (grid 8 x 128) ----
__global__ void k_prep0(const float* __restrict__ h0, const float* __restrict__ c0,
                        float* __restrict__ Hh, float* __restrict__ Cc,
                        unsigned* __restrict__ hbuf, unsigned* __restrict__ ctr){
  int b = blockIdx.x, tid = threadIdx.x;
  int i = b*128 + tid;
  Hh[i] = h0[i];
  Cc[i] = c0[i];
  if (i < 512){
    union { f16x2 h; unsigned u; } cv;
    cv.h = (f16x2){ (f16)h0[2*i], (f16)h0[2*i+1] };
    hbuf[i] = cv.u;
  }
  if (i < 3) ctr[i] = 0u;
}

// ---- CHUNK steps per launch: 64 blocks x 512 thr; 3 counter syncs/step ----
__global__ __launch_bounds__(NT) void k_multi(int t0,
    const unsigned* __restrict__ TP, const f16* __restrict__ Wah_h,
    const f16* __restrict__ Whh_h, const f16* __restrict__ Vt,
    const f16* __restrict__ Gp, const float* __restrict__ v_a,
    float* __restrict__ Hh, float* __restrict__ Cc,
    float* __restrict__ wahg, float* __restrict__ pbuf,
    unsigned* __restrict__ hbuf, unsigned* __restrict__ ctr,
    float* __restrict__ Pout)
{
  const int b = blockIdx.x, tid = threadIdx.x;
  __shared__ f16x8 hs8[128];       // h_t packed, swizzled [i*8+q]
  __shared__ f16x8 ps8[128];       // normalized p packed, swizzled [i*8+q]
  __shared__ float2 vwp[128];      // {tanh(wah), v*tanh(wah)}
  __shared__ float vas[128];
  __shared__ float gacc[64];
  __shared__ float g2[64];
  __shared__ float pown[16];
  __shared__ float hnl[16];
  __shared__ float wpart[8];
  __shared__ float invs;
  __shared__ float cst[16];

  const int l8 = tid >> 3, q8 = tid & 7;

  if (tid < 16) cst[tid] = Cc[b*16 + tid];
  if (tid < 128) vas[tid] = v_a[tid];

  for (int k = 0; k < CHUNK; ++k){
    const int t = t0 + k;
    const unsigned base = 64u*(unsigned)t;
    // P0: wait h ready (prev step's ctr2), load hbuf[t&1] -> hs8 swizzled
    if (tid == 0){
      while (aldu(&ctr[2]) < base) __builtin_amdgcn_s_sleep(1);
    }
    __syncthreads();
    if (tid < 128){
      const unsigned* hp = hbuf + (t&1)*512 + tid*4;
      union { unsigned u[4]; f16x8 v; } cv;
      cv.u[0]=aldu(hp); cv.u[1]=aldu(hp+1); cv.u[2]=aldu(hp+2); cv.u[3]=aldu(hp+3);
      hs8[(tid&15)*8 + (tid>>4)] = cv.v;
    }
    __syncthreads();
    // P1: produce wah dims {2b, 2b+1} (2 waves)
    if (tid < 128){
      int w = tid >> 6, lane = tid & 63;
      const f16x8* wr = (const f16x8*)(Wah_h + (size_t)(2*b+w)*HID) + lane;
      float acc = 0.f;
      #pragma unroll
      for (int i = 0; i < 2; ++i){
        int m = lane + i*64;
        f16x8 wv = wr[i*64];
        f16x8 hv = hs8[(m&15)*8 + (m>>4)];
        const f16x2* wp = (const f16x2*)&wv;
        const f16x2* hp = (const f16x2*)&hv;
        acc = __builtin_amdgcn_fdot2(wp[0], hp[0], acc, false);
        acc = __builtin_amdgcn_fdot2(wp[1], hp[1], acc, false);
        acc = __builtin_amdgcn_fdot2(wp[2], hp[2], acc, false);
        acc = __builtin_amdgcn_fdot2(wp[3], hp[3], acc, false);
      }
      acc += __shfl_xor(acc,1); acc += __shfl_xor(acc,2); acc += __shfl_xor(acc,4);
      acc += __shfl_xor(acc,8); acc += __shfl_xor(acc,16); acc += __shfl_xor(acc,32);
      if (lane == 0) astf(&wahg[(t&1)*128 + 2*b + w], acc);
    }
    __syncthreads();                                  // drain wah stores
    if (tid == 0)
      __hip_atomic_fetch_add(&ctr[0], 1u, __ATOMIC_RELAXED, __HIP_MEMORY_SCOPE_AGENT);
    // P2: gacc = Whh·h own 64 rows (hides c1 + wah flight)
    {
      const f16x8* wr = (const f16x8*)(Whh_h + (size_t)(b*64 + l8)*HID + q8*128);
      float acc = 0.f;
      #pragma unroll
      for (int i = 0; i < 16; ++i){
        f16x8 wv = wr[i];
        f16x8 hv = hs8[i*8 + q8];
        const f16x2* wp = (const f16x2*)&wv;
        const f16x2* hp = (const f16x2*)&hv;
        acc = __builtin_amdgcn_fdot2(wp[0], hp[0], acc, false);
        acc = __builtin_amdgcn_fdot2(wp[1], hp[1], acc, false);
        acc = __builtin_amdgcn_fdot2(wp[2], hp[2], acc, false);
        acc = __builtin_amdgcn_fdot2(wp[3], hp[3], acc, false);
      }
      acc += __shfl_xor(acc,1); acc += __shfl_xor(acc,2); acc += __shfl_xor(acc,4);
      if (q8 == 0) gacc[l8] = acc;
    }
    // P3: poll c1 (mostly satisfied), build vwp
    if (tid == 0){
      while (aldu(&ctr[0]) < base + 64u) __builtin_amdgcn_s_sleep(1);
    }
    __syncthreads();
    if (tid < 128){
      float w = aldf(&wahg[(t&1)*128 + tid]);
      float tw = tanh_f(w);
      vwp[tid] = make_float2(tw, vas[tid]*tw);
    }
    __syncthreads();
    // P4: scores for own 16 s-rows
    {
      int row = tid >> 5, l5 = tid & 31;
      const f16x8* tp8 = (const f16x8*)((const f16*)TP + ((size_t)(b*16+row)*ATTN + l5*4)*2);
      f16x8 tv = tp8[0];
      float sc = 0.f;
      #pragma unroll
      for (int u = 0; u < 4; ++u){
        float T  = (float)tv[2*u];
        float vT = (float)tv[2*u+1];
        float2 vw = vwp[l5*4 + u];
        float num = vT + vw.y;
        float den = fmaf(T, vw.x, 1.f);
        sc = fmaf(num, __builtin_amdgcn_rcpf(den), sc);
      }
      sc += __shfl_xor(sc,1); sc += __shfl_xor(sc,2); sc += __shfl_xor(sc,4);
      sc += __shfl_xor(sc,8); sc += __shfl_xor(sc,16);
      if (l5 == 0){
        float pv = __expf(sc);
        pown[row] = pv;
        astf(&pbuf[(t&1)*1024 + b*16 + row], pv);
      }
    }
    __syncthreads();                                  // drain p stores
    if (tid == 0)
      __hip_atomic_fetch_add(&ctr[1], 1u, __ATOMIC_RELAXED, __HIP_MEMORY_SCOPE_AGENT);
    // P5: poll c2, read all p, normalize, pack swizzled
    if (tid == 0){
      while (aldu(&ctr[1]) < base + 64u) __builtin_amdgcn_s_sleep(1);
    }
    __syncthreads();
    {
      float p0 = aldf(&pbuf[(t&1)*1024 + 2*tid]);
      float p1 = aldf(&pbuf[(t&1)*1024 + 2*tid + 1]);
      float s2 = p0 + p1;
      s2 += __shfl_xor(s2,1); s2 += __shfl_xor(s2,2); s2 += __shfl_xor(s2,4);
      s2 += __shfl_xor(s2,8); s2 += __shfl_xor(s2,16); s2 += __shfl_xor(s2,32);
      if ((tid & 63) == 0) wpart[tid >> 6] = s2;
      __syncthreads();
      if (tid == 0){
        float d = 0.f;
        #pragma unroll
        for (int kk = 0; kk < 8; ++kk) d += wpart[kk];
        invs = 1.f/d;
      }
      __syncthreads();
      float iv = invs;
      int q = tid >> 6, i8 = (tid & 63) >> 2, j = tid & 3;
      ((f16x2*)&ps8[i8*8 + q])[j] = (f16x2){ (f16)(p0*iv), (f16)(p1*iv) };
      if (tid < 16) Pout[(size_t)t*SRC + b*16 + tid] = pown[tid]*iv;
    }
    __syncthreads();
    // P6: gates = gacc + V·p̂ + G for own 64 rows
    {
      const f16x8* wr = (const f16x8*)(Vt + (size_t)(b*64 + l8)*SRC + q8*128);
      float acc = 0.f;
      #pragma unroll
      for (int i = 0; i < 16; ++i){
        f16x8 wv = wr[i];
        f16x8 pv = ps8[i*8 + q8];
        const f16x2* wp = (const f16x2*)&wv;
        const f16x2* pp = (const f16x2*)&pv;
        acc = __builtin_amdgcn_fdot2(wp[0], pp[0], acc, false);
        acc = __builtin_amdgcn_fdot2(wp[1], pp[1], acc, false);
        acc = __builtin_amdgcn_fdot2(wp[2], pp[2], acc, false);
        acc = __builtin_amdgcn_fdot2(wp[3], pp[3], acc, false);
      }
      acc += __shfl_xor(acc,1); acc += __shfl_xor(acc,2); acc += __shfl_xor(acc,4);
      if (q8 == 0) g2[l8] = acc + gacc[l8] + (float)Gp[(size_t)t*4096 + b*64 + l8];
    }
    __syncthreads();
    // P7: LSTM pointwise for own 16 j-dims; publish h
    if (tid < 16){
      float gi = g2[tid], gf = g2[16+tid], gg = g2[32+tid], go = g2[48+tid];
      float cn = sigm(gf)*cst[tid] + sigm(gi)*tanh_f(gg);
      float hn = sigm(go)*tanh_f(cn);
      cst[tid] = cn;
      hnl[tid] = hn;
      Hh[(size_t)(t+1)*HID + b*16 + tid] = hn;        // history for k_gemm
    }
    __syncthreads();
    if (tid < 8){
      union { f16x2 h; unsigned u; } cv;
      cv.h = (f16x2){ (f16)hnl[2*tid], (f16)hnl[2*tid+1] };
      astu(&hbuf[((t+1)&1)*512 + b*8 + tid], cv.u);
    }
    __syncthreads();                                  // drain h stores
    if (tid == 0)
      __hip_atomic_fetch_add(&ctr[2], 1u, __ATOMIC_RELAXED, __HIP_MEMORY_SCOPE_AGENT);
  }
  if (tid < 16) Cc[b*16 + tid] = cst[tid];
}

// ---- epilogue: logits = H @ W_out^T + b_out (bf16 MFMA, f32 in/out) ----
__global__ __launch_bounds__(256) void k_gemm(const float* __restrict__ A, const float* __restrict__ B,
                                              const float* __restrict__ bias, float* __restrict__ C){
  int bn = blockIdx.x, bm = blockIdx.y;
  int tid = threadIdx.x;
  int wid = tid>>6, lane = tid&63;
  int wr = wid>>1, wc = wid&1;
  int rowf = lane&15, kg = lane>>4;
  const int m_base = bm*128 + wr*64;
  const int n_base = bn*128 + wc*64;
  const float* Ap = A + (size_t)(m_base + rowf)*HID + kg*8;
  const float* Bp = B + (size_t)(n_base + rowf)*HID + kg*8;
  f32x4 acc[4][4];
  #pragma unroll
  for (int i=0;i<4;i++)
    #pragma unroll
    for (int jv=0;jv<4;jv++) acc[i][jv] = (f32x4){0.f,0.f,0.f,0.f};
  for (int kk=0; kk<HID; kk+=32){
    bf16x8v av[4], bv[4];
    #pragma unroll
    for (int mt=0;mt<4;mt++) av[mt] = cvt8(Ap + (size_t)mt*16*HID + kk);
    #pragma unroll
    for (int nt=0;nt<4;nt++) bv[nt] = cvt8(Bp + (size_t)nt*16*HID + kk);
    #pragma unroll
    for (int mt=0;mt<4;mt++)
      #pragma unroll
      for (int nt=0;nt<4;nt++)
        acc[mt][nt] = __builtin_amdgcn_mfma_f32_16x16x32_bf16(av[mt], bv[nt], acc[mt][nt], 0,0,0);
  }
  #pragma unroll
  for (int mt=0;mt<4;mt++){
    #pragma unroll
    for (int nt=0;nt<4;nt++){
      int n = n_base + nt*16 + rowf;
      float bo = bias[n];
      #pragma unroll
      for (int i=0;i<4;i++){
        int m = m_base + mt*16 + kg*4 + i;
        C[(size_t)m*VOCAB + n] = acc[mt][nt][i] + bo;
      }
    }
  }
}

extern "C" void kernel_launch(void* const* d_in, const int* in_sizes, int n_in,
                              void* d_out, int out_size, void* d_ws, size_t ws_size,
                              hipStream_t stream){
  const float* enc    = (const float*)d_in[0];
  const float* h0     = (const float*)d_in[1];
  const float* c0     = (const float*)d_in[2];
  const int*   sos    = (const int*)d_in[3];
  const int*   tgt    = (const int*)d_in[4];
  const float* embt   = (const float*)d_in[5];
  const float* Wa_enc = (const float*)d_in[6];
  const float* Wa_h   = (const float*)d_in[7];
  const float* v_a    = (const float*)d_in[8];
  const float* W_ih   = (const float*)d_in[9];
  const float* W_hh   = (const float*)d_in[10];
  const float* b_ih   = (const float*)d_in[11];
  const float* b_hh   = (const float*)d_in[12];
  const float* W_out  = (const float*)d_in[13];
  const float* b_out  = (const float*)d_in[14];

  float* ws   = (float*)d_ws;
  unsigned* TP = (unsigned*)(ws + OFF_TP);
  f16*   Gp   = (f16*)(ws + OFF_G);
  float* Hh   = ws + OFF_HH;
  float* Cc   = ws + OFF_CC;
  float* wahg = ws + OFF_WAHG;
  float* pbuf = ws + OFF_PB;
  unsigned* hbuf = (unsigned*)(ws + OFF_HBUF);
  unsigned* ctr  = (unsigned*)(ws + OFF_CTR);
  f16*   Wah_h= (f16*)(ws + OFF_WAHW);
  f16*   Whh_h= (f16*)(ws + OFF_WHH);
  f16*   Vt   = (f16*)(ws + OFF_VT);

  float* out_logits = (float*)d_out;
  float* out_attn   = out_logits + (size_t)TGT*VOCAB;

  k_encTP   <<<64, 128, 0, stream>>>(enc, Wa_enc, v_a, TP);
  k_gbase   <<<dim3(16, 32), 256, 0, stream>>>(sos, tgt, embt, W_ih, b_ih, b_hh, Gp);
  k_cvt_whh <<<4096, 128, 0, stream>>>(W_hh, Whh_h);
  k_cvt_wah <<<128, 128, 0, stream>>>(Wa_h, Wah_h);
  k_gemmV   <<<dim3(8, 32), 256, 0, stream>>>(W_ih, enc, Vt);
  k_prep0   <<<8, 128, 0, stream>>>(h0, c0, Hh, Cc, hbuf, ctr);

  for (int t0 = 0; t0 < TGT; t0 += CHUNK){
    k_multi<<<NB, NT, 0, stream>>>(t0, TP, Wah_h, Whh_h, Vt, Gp, v_a,
                                   Hh, Cc, wahg, pbuf, hbuf, ctr, out_attn);
  }

  k_gemm<<<dim3(250, 4), 256, 0, stream>>>(Hh + HID, W_out, b_out, out_logits);
}